// Round 11
// baseline (319.265 us; speedup 1.0000x reference)
//
#include <hip/hip_runtime.h>
#include <hip/hip_bf16.h>
#include <hip/hip_fp16.h>
#include <stdint.h>

#define N_NODESC 25000
#define N_EDGESC 400000
#define N_GRAPHSC 64
#define F_INC 128
#define HIDC 512
#define PSTRIDE 1600000   // elements per 64-col panel: 25000*64

typedef __attribute__((ext_vector_type(8))) short short8;
typedef __attribute__((ext_vector_type(8))) _Float16 half8;
typedef __attribute__((ext_vector_type(4))) float f32x4;

__device__ __forceinline__ unsigned short f2h(float f) {
  return __half_as_ushort(__float2half_rn(f));
}

// ================= fused prep (1 launch):
//  blocks [0,1563): degree count via atomicAdd on UNIFORM-init deg (poison-agnostic;
//                   true degree recovered in scan via sentinel deg[25000])
//  blocks [1563,4688): x -> fp16 panel-major
//  blocks [4688,4848): weight transposes (LDS tiles)
//  blocks [4848,4976): zero gsum
__global__ __launch_bounds__(256)
void prep_kernel(const float* __restrict__ x, const int* __restrict__ ei,
                 const float* __restrict__ W1rel, const float* __restrict__ W1root,
                 const float* __restrict__ W2rel, const float* __restrict__ W2root,
                 unsigned short* __restrict__ xp, unsigned short* __restrict__ W1T,
                 unsigned short* __restrict__ W2T, int* __restrict__ deg,
                 float* __restrict__ gsum) {
  int blk = blockIdx.x, t = threadIdx.x;
  if (blk < 1563) {                              // degree histogram (no pre-zero needed)
    int e = blk * 256 + t;
    if (e < N_EDGESC) atomicAdd(&deg[ei[N_EDGESC + e]], 1);
  } else if (blk < 4688) {                       // 3125 blocks: 3.2M elems / 4
    int idx = ((blk - 1563) * 256 + t) * 4;
    int node = idx >> 7;
    int col = idx & 127;
    float4 v = *(const float4*)(x + idx);
    ushort4 o;
    o.x = f2h(v.x); o.y = f2h(v.y); o.z = f2h(v.z); o.w = f2h(v.w);
    *(ushort4*)(xp + (size_t)(col >> 6) * PSTRIDE + (size_t)node * 64 + (col & 63)) = o;
  } else if (blk < 4848) {                       // 160 blocks: weight transposes
    __shared__ float tile[64][65];
    int b2 = blk - 4688;
    const float* src;
    unsigned short* dst;
    int n0, k0, Kout;
    if (b2 < 128) {                              // W2: k-tiles 16, n-tiles 8
      int kt = b2 >> 3, nt = b2 & 7;
      k0 = kt * 64; n0 = nt * 64;
      src = (k0 < 512) ? (W2rel + (size_t)k0 * 512) : (W2root + (size_t)(k0 - 512) * 512);
      dst = W2T; Kout = 1024;
    } else {                                     // W1: k-tiles 4, n-tiles 8
      int b = b2 - 128;
      int kt = b >> 3, nt = b & 7;
      k0 = kt * 64; n0 = nt * 64;
      src = (k0 < 128) ? (W1rel + (size_t)k0 * 512) : (W1root + (size_t)(k0 - 128) * 512);
      dst = W1T; Kout = 256;
    }
    int c = t & 63;
    int r4 = t >> 6;
#pragma unroll
    for (int rr = 0; rr < 64; rr += 4) {
      int row = rr + r4;
      tile[c][row] = src[(size_t)row * 512 + n0 + c];
    }
    __syncthreads();
#pragma unroll
    for (int rr = 0; rr < 64; rr += 4) {
      int nrow = rr + r4;
      dst[(size_t)(n0 + nrow) * Kout + k0 + c] = f2h(tile[nrow][c]);
    }
  } else {                                       // 128 blocks: gsum 64x512
    int i = (blk - 4848) * 256 + t;
    if (i < N_GRAPHSC * HIDC) gsum[i] = 0.f;
  }
}

// single-block scan v3 — COALESCED (R9-verified, -22us): wave w owns nodes
// [w*1600, w*1600+1600), lane l handles i*64+l. Per-group shfl_up inclusive
// scans; cross-wave bases via 16-value wave-0 scan; striped degree bins.
__global__ __launch_bounds__(1024)
void scan_kernel(const int* __restrict__ deg, int* __restrict__ indptr, int* __restrict__ cursor,
                 int* __restrict__ sorted) {
  __shared__ int binsS[1024];    // [256 bins][4 stripes], flat f = bin*4 + stripe
  __shared__ int scan2[1024];
  __shared__ int Wsh[16];        // per-wave degree totals
  __shared__ int waveBase[16];   // exclusive prefix of Wsh
  __shared__ int gTot;
  const int t = threadIdx.x;
  const int w = t >> 6;
  const int lane = t & 63;
  const int stripe = t & 3;
  const int nbase = w * 1600;
  const unsigned ub = (unsigned)deg[N_NODESC];   // uniform init value (poison or 0)
  binsS[t] = 0;
  __syncthreads();

  // Phase A: coalesced loads, per-thread dl[], wave totals, striped histogram
  int dl[25];
  int tw = 0;
#pragma unroll
  for (int i = 0; i < 25; ++i) {
    int idx = nbase + i * 64 + lane;
    int d = (idx < N_NODESC) ? (int)((unsigned)deg[idx] - ub) : 0;
    dl[i] = d;
    if (idx < N_NODESC) {
      tw += d;
      atomicAdd(&binsS[(d > 255 ? 255 : d) * 4 + stripe], 1);
    }
  }
#pragma unroll
  for (int off = 32; off > 0; off >>= 1) tw += __shfl_xor(tw, off);
  if (lane == 0) Wsh[w] = tw;
  __syncthreads();               // histogram + Wsh complete

  // Phase B(1): wave-0 scans the 16 wave totals (no barrier inside)
  if (t < 16) {
    int v = Wsh[t];
    int s = v;
#pragma unroll
    for (int off = 1; off < 16; off <<= 1) {
      int u = __shfl_up(s, off);
      if (t >= off) s += u;
    }
    waveBase[t] = s - v;
    if (t == 15) gTot = s;
  }
  // Phase B(2): 1024-wide exclusive prefix of striped bins
  int bv = binsS[t];
  scan2[t] = bv;
  __syncthreads();
  for (int off = 1; off < 1024; off <<= 1) {
    int v2 = (t >= off) ? scan2[t - off] : 0;
    __syncthreads();
    scan2[t] += v2;
    __syncthreads();
  }
  binsS[t] = scan2[t] - bv;      // exclusive striped placement bases
  __syncthreads();

  // Phase C: coalesced indptr/cursor writes + striped placement
  int run = waveBase[w];
#pragma unroll
  for (int i = 0; i < 25; ++i) {
    int idx = nbase + i * 64 + lane;
    int d = dl[i];
    int s = d;
#pragma unroll
    for (int off = 1; off < 64; off <<= 1) {
      int u = __shfl_up(s, off);
      if (lane >= off) s += u;
    }
    int excl = run + s - d;
    if (idx < N_NODESC) {
      indptr[idx] = excl;
      cursor[idx] = excl;
      int fb = (d > 255 ? 255 : d) * 4 + stripe;
      int pos = atomicAdd(&binsS[fb], 1);
      sorted[pos] = idx;
    }
    run += __shfl(s, 63);        // group total
  }
  if (t == 0) indptr[N_NODESC] = gTot;
}

// packed edge meta: src (16b) | fp16 weight (16b)
__global__ void fill_kernel(const int* __restrict__ ei, const float* __restrict__ ea,
                            int* __restrict__ cursor, unsigned* __restrict__ emeta) {
  int e = blockIdx.x * blockDim.x + threadIdx.x;
  if (e >= N_EDGESC) return;
  int dst = ei[N_EDGESC + e];
  int pos = atomicAdd(&cursor[dst], 1);
  unsigned short hw = __half_as_ushort(__float2half_rn(ea[e]));
  emeta[pos] = (unsigned)ei[e] | ((unsigned)hw << 16);
}

// ================= panel-major CSR gather (L2-blocked, 8 nodes per wave, fp16) =====
// 4-edge unroll, 2 independent accumulator banks (R7-verified best variant).
__global__ __launch_bounds__(256)
void agg_gather_s(const unsigned short* __restrict__ feat, const int* __restrict__ indptr,
                  const unsigned* __restrict__ emeta, const int* __restrict__ sorted,
                  unsigned short* __restrict__ outp, int lgP) {
  int panel = blockIdx.x & ((1 << lgP) - 1);
  int nidx = (blockIdx.x >> lgP) * 32 + (threadIdx.x >> 3);   // 32 node-slots / block
  if (nidx >= N_NODESC) return;
  int c8 = threadIdx.x & 7;
  int node = sorted[nidx];
  int beg = indptr[node];
  int deg = indptr[node + 1] - beg;
  const unsigned* mp = emeta + beg;
  const char* fb = (const char*)(feat + (size_t)panel * PSTRIDE);
  unsigned coff = c8 * 16u;
  float acc0[8] = {}, acc1[8] = {};
  int j = 0;
  for (; j + 4 <= deg; j += 4) {
    unsigned m0_ = mp[j];
    unsigned m1_ = mp[j + 1];
    unsigned m2_ = mp[j + 2];
    unsigned m3_ = mp[j + 3];
    half8 v0 = *(const half8*)(fb + (m0_ & 0xffffu) * 128u + coff);
    half8 v1 = *(const half8*)(fb + (m1_ & 0xffffu) * 128u + coff);
    half8 v2 = *(const half8*)(fb + (m2_ & 0xffffu) * 128u + coff);
    half8 v3 = *(const half8*)(fb + (m3_ & 0xffffu) * 128u + coff);
    float w0 = __half2float(__ushort_as_half((unsigned short)(m0_ >> 16)));
    float w1 = __half2float(__ushort_as_half((unsigned short)(m1_ >> 16)));
    float w2 = __half2float(__ushort_as_half((unsigned short)(m2_ >> 16)));
    float w3 = __half2float(__ushort_as_half((unsigned short)(m3_ >> 16)));
#pragma unroll
    for (int c = 0; c < 8; ++c) acc0[c] += (float)v0[c] * w0;
#pragma unroll
    for (int c = 0; c < 8; ++c) acc1[c] += (float)v1[c] * w1;
#pragma unroll
    for (int c = 0; c < 8; ++c) acc0[c] += (float)v2[c] * w2;
#pragma unroll
    for (int c = 0; c < 8; ++c) acc1[c] += (float)v3[c] * w3;
  }
  if (j + 2 <= deg) {
    unsigned mA = mp[j];
    unsigned mB = mp[j + 1];
    half8 vA = *(const half8*)(fb + (mA & 0xffffu) * 128u + coff);
    half8 vB = *(const half8*)(fb + (mB & 0xffffu) * 128u + coff);
    float wA = __half2float(__ushort_as_half((unsigned short)(mA >> 16)));
    float wB = __half2float(__ushort_as_half((unsigned short)(mB >> 16)));
#pragma unroll
    for (int c = 0; c < 8; ++c) acc0[c] += (float)vA[c] * wA;
#pragma unroll
    for (int c = 0; c < 8; ++c) acc1[c] += (float)vB[c] * wB;
    j += 2;
  }
  if (j < deg) {
    unsigned mA = mp[j];
    half8 vA = *(const half8*)(fb + (mA & 0xffffu) * 128u + coff);
    float wA = __half2float(__ushort_as_half((unsigned short)(mA >> 16)));
#pragma unroll
    for (int c = 0; c < 8; ++c) acc0[c] += (float)vA[c] * wA;
  }
  half8 o;
#pragma unroll
  for (int c = 0; c < 8; ++c) o[c] = (_Float16)(acc0[c] + acc1[c]);
  *(half8*)(outp + (size_t)panel * PSTRIDE + (size_t)node * 64 + c8 * 8) = o;
}

// ---- XCD swizzle for 392-block grid (98 m-tiles of 256 x 4 n-tiles of 128); 392=8*49.
__device__ __forceinline__ void gemm_map4(int b, int& m0, int& n0) {
  int g = (b & 7) * 49 + (b >> 3);   // contiguous chunk per XCD
  m0 = (g >> 2) << 8;                 // 0..24832 (98 m-tiles of 256)
  n0 = (g & 3) << 7;                  // 0,128,256,384
}

// ---- B staging (256 thr): linear LDS dest, pre-swizzled global source
//      (chunk c = (s&7) ^ (row&7)) -- proven conflict-free.  128x64 = 16 KB,
//      4 loads/thread.  A is NOT staged (direct-from-global, panel-major
//      rows are K-contiguous so fragments are plain 16B loads -> L1/L2).
__device__ __forceinline__ void stage_b4(const short* BT, int n0, int K, int kbase,
                                         short* dst, int wave, int lane) {
#pragma unroll
  for (int i = 0; i < 4; ++i) {
    int s = ((i * 4 + wave) << 6) + lane;
    int row = s >> 3;                  // 0..127
    int c = (s & 7) ^ (row & 7);
    const short* gp = BT + (size_t)(n0 + row) * K + kbase + (c << 3);
    __builtin_amdgcn_global_load_lds(
        (const __attribute__((address_space(1))) void*)gp,
        (__attribute__((address_space(3))) void*)(dst + ((i * 4 + wave) << 9)),
        16, 0, 0);
  }
}

__device__ __forceinline__ const short* apan_sel(const short* A0, const short* A1,
                                                 int S, int kt) {
  int kb = kt << 6;
  const short* Ab = (kb < S) ? A0 : A1;
  int koff = (kb < S) ? kb : kb - S;
  return Ab + (size_t)(koff >> 6) * PSTRIDE;
}

// raw barrier + compiler memory fence
__device__ __forceinline__ void wg_barrier() {
  asm volatile("" ::: "memory");
  __builtin_amdgcn_s_barrier();
  asm volatile("" ::: "memory");
}

// ---- gemm_core v4: BM=256, BN=128, BK=64, 256 thr (4 waves 2m x 2n, wave-tile
//      128x64, 8x4 frags).  A-operand DIRECT FROM GLOBAL (K-contiguous panel
//      rows; 16B loads served by L1/L2, 8 outstanding per lane per phase) --
//      removes A from the LDS pipe entirely.  LDS = B only (16 KB, XOR-swizzled).
//      LDS traffic/K-tile: 48 KB (was 144 KB) -> bound shifts to L1 ~1024 cyc
//      vs old LDS 1690 cyc, predicted ~1.6x on the GEMM.
__device__ __forceinline__ void gemm_core(const short* A0, const short* A1,
                                          const short* BT, int M, int S,
                                          int m0, int n0, short* Bs,
                                          f32x4 (&acc)[8][4]) {
  const int K = 2 * S;
  const int nk = K >> 6;              // 4 (GEMM1) / 16 (GEMM2)
  const int tid = threadIdx.x;
  const int wave = tid >> 6;
  const int lane = tid & 63;
  const int quad = lane >> 4;
  const int r = lane & 15;
  const int wm = (wave >> 1) << 7;    // 0 or 128
  const int wn = (wave & 1) << 6;     // 0 or 64

  // A: clamped global row index per tm (row*64 elems per panel row)
  int arow[8];
#pragma unroll
  for (int tm = 0; tm < 8; ++tm) {
    int rg = m0 + wm + tm * 16 + r;
    arow[tm] = (rg > M - 1) ? (M - 1) : rg;
  }
  // B: LDS fragment short-offsets (XOR-swizzled), static-indexed
  int boff[2][4];
#pragma unroll
  for (int p = 0; p < 2; ++p) {
#pragma unroll
    for (int tn = 0; tn < 4; ++tn) {
      int nl = wn + tn * 16 + r;       // 0..127
      int c = (p << 2) + quad;
      boff[p][tn] = (nl * 8 + (c ^ (nl & 7))) * 8;
    }
  }

  for (int t = 0; t < nk; ++t) {
    const short* Apan = apan_sel(A0, A1, S, t);
    stage_b4(BT, n0, K, t << 6, Bs, wave, lane);
    asm volatile("s_waitcnt vmcnt(0)");
    wg_barrier();
    // ---------- phase 0 (ks = 0): 8 global A loads + 4 LDS B reads + 32 MFMA
    {
      half8 af[8], bf[4];
      const int c0 = quad << 3;        // k-offset within 64-row: (0*4+quad)*8
#pragma unroll
      for (int tm = 0; tm < 8; ++tm)
        af[tm] = *(const half8*)(Apan + (size_t)arow[tm] * 64 + c0);
#pragma unroll
      for (int tn = 0; tn < 4; ++tn) bf[tn] = *(const half8*)&Bs[boff[0][tn]];
      __builtin_amdgcn_s_setprio(1);
#pragma unroll
      for (int tm = 0; tm < 8; ++tm)
#pragma unroll
        for (int tn = 0; tn < 4; ++tn)
          acc[tm][tn] = __builtin_amdgcn_mfma_f32_16x16x32_f16(af[tm], bf[tn], acc[tm][tn], 0, 0, 0);
      __builtin_amdgcn_s_setprio(0);
    }
    // ---------- phase 1 (ks = 1): 8 global A loads + 4 LDS B reads + 32 MFMA
    {
      half8 af[8], bf[4];
      const int c1 = (4 + quad) << 3;  // (1*4+quad)*8
#pragma unroll
      for (int tm = 0; tm < 8; ++tm)
        af[tm] = *(const half8*)(Apan + (size_t)arow[tm] * 64 + c1);
#pragma unroll
      for (int tn = 0; tn < 4; ++tn) bf[tn] = *(const half8*)&Bs[boff[1][tn]];
      __builtin_amdgcn_s_setprio(1);
#pragma unroll
      for (int tm = 0; tm < 8; ++tm)
#pragma unroll
        for (int tn = 0; tn < 4; ++tn)
          acc[tm][tn] = __builtin_amdgcn_mfma_f32_16x16x32_f16(af[tm], bf[tn], acc[tm][tn], 0, 0, 0);
      __builtin_amdgcn_s_setprio(0);
    }
    wg_barrier();   // protect single-buffered B LDS before next stage
  }
}

// ---------------- fp16 MFMA GEMM (A operands PANEL-MAJOR): h1p = relu([A0|A1]@BT^T + b)
__global__ __launch_bounds__(256, 2)
void gemm_bt_relu(const short* __restrict__ A0, const short* __restrict__ A1,
                  const short* __restrict__ BT, const float* __restrict__ bias,
                  unsigned short* __restrict__ Outp, int M, int S) {
  __shared__ __align__(16) short Bs[128 * 64];   // 16 KB
  int m0, n0;
  gemm_map4(blockIdx.x, m0, n0);
  const int wave = threadIdx.x >> 6;
  const int lane = threadIdx.x & 63;
  const int quad = lane >> 4;
  const int r = lane & 15;
  const int wm = (wave >> 1) << 7;
  const int wn = (wave & 1) << 6;

  f32x4 acc[8][4] = {};
  gemm_core(A0, A1, BT, M, S, m0, n0, Bs, acc);

#pragma unroll
  for (int tm = 0; tm < 8; ++tm) {
    int rowb = m0 + wm + tm * 16 + quad * 4;
#pragma unroll
    for (int tn = 0; tn < 4; ++tn) {
      int col = n0 + wn + tn * 16 + r;
      float bv = bias[col];
      unsigned short* obase = Outp + (size_t)(col >> 6) * PSTRIDE + (col & 63);
#pragma unroll
      for (int reg = 0; reg < 4; ++reg) {
        int rr = rowb + reg;
        if (rr < M) {
          float v = acc[tm][tn][reg] + bv;
          v = v > 0.f ? v : 0.f;
          obase[(size_t)rr * 64] = f2h(v);
        }
      }
    }
  }
}

// ---------------- GEMM2 + fused mean-pool (A panel-major): gsum += per-graph col sums
__global__ __launch_bounds__(256, 2)
void gemm_bt_pool(const short* __restrict__ A0, const short* __restrict__ A1,
                  const short* __restrict__ BT, const float* __restrict__ bias,
                  const int* __restrict__ batch, float* __restrict__ gsum, int M, int S) {
  __shared__ __align__(16) short Bs[128 * 64];   // 16 KB
  int m0, n0;
  gemm_map4(blockIdx.x, m0, n0);
  const int wave = threadIdx.x >> 6;
  const int lane = threadIdx.x & 63;
  const int quad = lane >> 4;
  const int r = lane & 15;
  const int wm = (wave >> 1) << 7;
  const int wn = (wave & 1) << 6;

  f32x4 acc[8][4] = {};
  gemm_core(A0, A1, BT, M, S, m0, n0, Bs, acc);

  // epilogue: relu(+bias), zero invalid rows, per-graph column sums -> atomicAdd(gsum)
  int gid[8][4];
#pragma unroll
  for (int tm = 0; tm < 8; ++tm) {
    int rowb = m0 + wm + tm * 16 + quad * 4;
#pragma unroll
    for (int reg = 0; reg < 4; ++reg) {
      int rr = rowb + reg;
      gid[tm][reg] = batch[rr < M ? rr : (M - 1)];
    }
#pragma unroll
    for (int tn = 0; tn < 4; ++tn) {
      float bv = bias[n0 + wn + tn * 16 + r];
#pragma unroll
      for (int reg = 0; reg < 4; ++reg) {
        int rr = rowb + reg;
        float v = acc[tm][tn][reg] + bv;
        v = v > 0.f ? v : 0.f;
        acc[tm][tn][reg] = (rr < M) ? v : 0.f;
      }
    }
  }
  int g_lo = batch[m0 < M ? m0 : (M - 1)];
  int g_hi = batch[(m0 + 255) < M ? (m0 + 255) : (M - 1)];
  for (int g = g_lo; g <= g_hi; ++g) {
#pragma unroll
    for (int tn = 0; tn < 4; ++tn) {
      float s = 0.f;
#pragma unroll
      for (int tm = 0; tm < 8; ++tm)
#pragma unroll
        for (int reg = 0; reg < 4; ++reg)
          s += (gid[tm][reg] == g) ? acc[tm][tn][reg] : 0.f;
      s += __shfl_xor(s, 16);
      s += __shfl_xor(s, 32);
      if (quad == 0)
        atomicAdd(&gsum[(size_t)g * HIDC + n0 + wn + tn * 16 + r], s);
    }
  }
}

// ---------------- MLP head (256 threads: 4-way split over the 512-dim input)
__global__ __launch_bounds__(256)
void mlp_kernel(const float* __restrict__ gsum, const int* __restrict__ batch,
                const float* __restrict__ Wl1, const float* __restrict__ bl1,
                const float* __restrict__ Wl2, const float* __restrict__ bl2,
                const float* __restrict__ Wl3, const float* __restrict__ bl3,
                float* __restrict__ out) {
  int gi = blockIdx.x;
  int t = threadIdx.x;
  int unit = t & 63;
  int part = t >> 6;  // 4 parts of 128
  __shared__ float red[4][64];
  __shared__ float h1s[64];
  __shared__ float h2s[16];
  int lo = 0, hi = N_NODESC;
  while (lo < hi) { int mid = (lo + hi) >> 1; if (batch[mid] < gi) lo = mid + 1; else hi = mid; }
  int start = lo;
  hi = N_NODESC;
  while (lo < hi) { int mid = (lo + hi) >> 1; if (batch[mid] < gi + 1) lo = mid + 1; else hi = mid; }
  float inv = 1.0f / fmaxf((float)(lo - start), 1.0f);
  const float* gr = gsum + gi * HIDC;
  float acc = 0.f;
  for (int j = part * 128; j < (part + 1) * 128; ++j)
    acc += gr[j] * Wl1[j * 64 + unit];
  red[part][unit] = acc;
  __syncthreads();
  if (t < 64) {
    float a = bl1[t] + (red[0][t] + red[1][t] + red[2][t] + red[3][t]) * inv;
    h1s[t] = fmaxf(a, 0.f);
  }
  __syncthreads();
  if (t < 16) {
    float a = bl2[t];
    for (int j = 0; j < 64; ++j) a += h1s[j] * Wl2[j * 16 + t];
    h2s[t] = fmaxf(a, 0.f);
  }
  __syncthreads();
  if (t == 0) {
    float a = bl3[0];
    for (int j = 0; j < 16; ++j) a += h2s[j] * Wl3[j];
    out[gi] = a;
  }
}

extern "C" void kernel_launch(void* const* d_in, const int* in_sizes, int n_in,
                              void* d_out, int out_size, void* d_ws, size_t ws_size,
                              hipStream_t stream) {
  const float* x      = (const float*)d_in[0];
  const int*   ei     = (const int*)d_in[1];
  const float* ea     = (const float*)d_in[2];
  const int*   batch  = (const int*)d_in[3];
  const float* W1rel  = (const float*)d_in[4];
  const float* b1     = (const float*)d_in[5];
  const float* W1root = (const float*)d_in[6];
  const float* W2rel  = (const float*)d_in[7];
  const float* b2     = (const float*)d_in[8];
  const float* W2root = (const float*)d_in[9];
  const float* Wl1    = (const float*)d_in[10];
  const float* bl1    = (const float*)d_in[11];
  const float* Wl2    = (const float*)d_in[12];
  const float* bl2    = (const float*)d_in[13];
  const float* Wl3    = (const float*)d_in[14];
  const float* bl3    = (const float*)d_in[15];
  float* out = (float*)d_out;

  // workspace layout (bytes, 16B-aligned). All node features fp16 PANEL-MAJOR [P][25000][64].
  char* ws = (char*)d_ws;
  unsigned short* xp     = (unsigned short*)(ws + 0);           //  6.4 MB (2 panels)
  unsigned short* agg1p  = (unsigned short*)(ws + 6400000);     //  6.4 MB (2 panels)
  unsigned short* h1p    = (unsigned short*)(ws + 12800000);    // 25.6 MB (8 panels)
  unsigned short* agg2p  = (unsigned short*)(ws + 38400000);    // 25.6 MB (8 panels)
  unsigned short* W1T    = (unsigned short*)(ws + 64000000);    // 256 KB
  unsigned short* W2T    = (unsigned short*)(ws + 64262144);    //   1 MB
  float*          gsum   = (float*)(ws + 65310720);             // 128 KB
  int*            deg    = (int*)(ws + 65441792);               // 100 KB + sentinel
  int*            cursor = (int*)(ws + 65541796);               // 100 KB
  int*            indptr = (int*)(ws + 65641796);               // 100 KB+16
  unsigned*       emeta  = (unsigned*)(ws + 65741812);          //  1.6 MB (exact CSR)
  int*            sorted = (int*)(ws + 67341812);               // 100 KB

  // 1) fused prep: deg histogram (uniform-base) + x->fp16 panels + wt + zero gsum
  prep_kernel<<<4976, 256, 0, stream>>>(x, ei, W1rel, W1root, W2rel, W2root,
                                        xp, W1T, W2T, deg, gsum);
  // 2) scan v3 (coalesced; + base subtraction, striped counting sort by degree)
  scan_kernel<<<1, 1024, 0, stream>>>(deg, indptr, cursor, sorted);
  // 3) CSR fill
  fill_kernel<<<(N_EDGESC + 255) / 256, 256, 0, stream>>>(ei, ea, cursor, emeta);

  // 4) layer-1 aggregation: 2 panels (panel = blk&1); 32 nodes/block
  const int NBLK = (N_NODESC + 31) / 32;   // 782
  agg_gather_s<<<NBLK * 2, 256, 0, stream>>>(xp, indptr, emeta, sorted, agg1p, 1);

  // 5) GEMM1: h1p = relu([agg1|x] @ [W1rel;W1root] + b1)   (M=25000, K=256, N=512)
  gemm_bt_relu<<<392, 256, 0, stream>>>((const short*)agg1p, (const short*)xp,
                                        (const short*)W1T, b1, h1p, N_NODESC, 128);

  // 6) layer-2 aggregation: 8 panels (panel = blk&7 -> per-XCD L2-resident)
  agg_gather_s<<<NBLK * 8, 256, 0, stream>>>(h1p, indptr, emeta, sorted, agg2p, 3);

  // 7) GEMM2 + fused mean-pool
  gemm_bt_pool<<<392, 256, 0, stream>>>((const short*)agg2p, (const short*)h1p,
                                        (const short*)W2T, b2, batch, gsum, N_NODESC, 512);

  // 8) MLP head (divides by counts)
  mlp_kernel<<<N_GRAPHSC, 256, 0, stream>>>(gsum, batch, Wl1, bl1, Wl2, bl2, Wl3, bl3, out);
}

// Round 12
// 270.515 us; speedup vs baseline: 1.1802x; 1.1802x over previous
//
#include <hip/hip_runtime.h>
#include <hip/hip_bf16.h>
#include <hip/hip_fp16.h>
#include <stdint.h>

#define N_NODESC 25000
#define N_EDGESC 400000
#define N_GRAPHSC 64
#define F_INC 128
#define HIDC 512
#define PSTRIDE 1600000   // elements per 64-col panel: 25000*64

typedef __attribute__((ext_vector_type(8))) short short8;
typedef __attribute__((ext_vector_type(8))) _Float16 half8;
typedef __attribute__((ext_vector_type(4))) float f32x4;

__device__ __forceinline__ unsigned short f2h(float f) {
  return __half_as_ushort(__float2half_rn(f));
}

// ================= fused prep (1 launch):
//  blocks [0,1563): degree count via atomicAdd on UNIFORM-init deg (poison-agnostic;
//                   true degree recovered in scan via sentinel deg[25000])
//  blocks [1563,4688): x -> fp16 panel-major
//  blocks [4688,4848): weight transposes (LDS tiles)
//  blocks [4848,4976): zero gsum
__global__ __launch_bounds__(256)
void prep_kernel(const float* __restrict__ x, const int* __restrict__ ei,
                 const float* __restrict__ W1rel, const float* __restrict__ W1root,
                 const float* __restrict__ W2rel, const float* __restrict__ W2root,
                 unsigned short* __restrict__ xp, unsigned short* __restrict__ W1T,
                 unsigned short* __restrict__ W2T, int* __restrict__ deg,
                 float* __restrict__ gsum) {
  int blk = blockIdx.x, t = threadIdx.x;
  if (blk < 1563) {                              // degree histogram (no pre-zero needed)
    int e = blk * 256 + t;
    if (e < N_EDGESC) atomicAdd(&deg[ei[N_EDGESC + e]], 1);
  } else if (blk < 4688) {                       // 3125 blocks: 3.2M elems / 4
    int idx = ((blk - 1563) * 256 + t) * 4;
    int node = idx >> 7;
    int col = idx & 127;
    float4 v = *(const float4*)(x + idx);
    ushort4 o;
    o.x = f2h(v.x); o.y = f2h(v.y); o.z = f2h(v.z); o.w = f2h(v.w);
    *(ushort4*)(xp + (size_t)(col >> 6) * PSTRIDE + (size_t)node * 64 + (col & 63)) = o;
  } else if (blk < 4848) {                       // 160 blocks: weight transposes
    __shared__ float tile[64][65];
    int b2 = blk - 4688;
    const float* src;
    unsigned short* dst;
    int n0, k0, Kout;
    if (b2 < 128) {                              // W2: k-tiles 16, n-tiles 8
      int kt = b2 >> 3, nt = b2 & 7;
      k0 = kt * 64; n0 = nt * 64;
      src = (k0 < 512) ? (W2rel + (size_t)k0 * 512) : (W2root + (size_t)(k0 - 512) * 512);
      dst = W2T; Kout = 1024;
    } else {                                     // W1: k-tiles 4, n-tiles 8
      int b = b2 - 128;
      int kt = b >> 3, nt = b & 7;
      k0 = kt * 64; n0 = nt * 64;
      src = (k0 < 128) ? (W1rel + (size_t)k0 * 512) : (W1root + (size_t)(k0 - 128) * 512);
      dst = W1T; Kout = 256;
    }
    int c = t & 63;
    int r4 = t >> 6;
#pragma unroll
    for (int rr = 0; rr < 64; rr += 4) {
      int row = rr + r4;
      tile[c][row] = src[(size_t)row * 512 + n0 + c];
    }
    __syncthreads();
#pragma unroll
    for (int rr = 0; rr < 64; rr += 4) {
      int nrow = rr + r4;
      dst[(size_t)(n0 + nrow) * Kout + k0 + c] = f2h(tile[nrow][c]);
    }
  } else {                                       // 128 blocks: gsum 64x512
    int i = (blk - 4848) * 256 + t;
    if (i < N_GRAPHSC * HIDC) gsum[i] = 0.f;
  }
}

// single-block scan v3 — COALESCED (R9-verified, -22us): wave w owns nodes
// [w*1600, w*1600+1600), lane l handles i*64+l. Per-group shfl_up inclusive
// scans; cross-wave bases via 16-value wave-0 scan; striped degree bins.
__global__ __launch_bounds__(1024)
void scan_kernel(const int* __restrict__ deg, int* __restrict__ indptr, int* __restrict__ cursor,
                 int* __restrict__ sorted) {
  __shared__ int binsS[1024];    // [256 bins][4 stripes], flat f = bin*4 + stripe
  __shared__ int scan2[1024];
  __shared__ int Wsh[16];        // per-wave degree totals
  __shared__ int waveBase[16];   // exclusive prefix of Wsh
  __shared__ int gTot;
  const int t = threadIdx.x;
  const int w = t >> 6;
  const int lane = t & 63;
  const int stripe = t & 3;
  const int nbase = w * 1600;
  const unsigned ub = (unsigned)deg[N_NODESC];   // uniform init value (poison or 0)
  binsS[t] = 0;
  __syncthreads();

  // Phase A: coalesced loads, per-thread dl[], wave totals, striped histogram
  int dl[25];
  int tw = 0;
#pragma unroll
  for (int i = 0; i < 25; ++i) {
    int idx = nbase + i * 64 + lane;
    int d = (idx < N_NODESC) ? (int)((unsigned)deg[idx] - ub) : 0;
    dl[i] = d;
    if (idx < N_NODESC) {
      tw += d;
      atomicAdd(&binsS[(d > 255 ? 255 : d) * 4 + stripe], 1);
    }
  }
#pragma unroll
  for (int off = 32; off > 0; off >>= 1) tw += __shfl_xor(tw, off);
  if (lane == 0) Wsh[w] = tw;
  __syncthreads();               // histogram + Wsh complete

  // Phase B(1): wave-0 scans the 16 wave totals (no barrier inside)
  if (t < 16) {
    int v = Wsh[t];
    int s = v;
#pragma unroll
    for (int off = 1; off < 16; off <<= 1) {
      int u = __shfl_up(s, off);
      if (t >= off) s += u;
    }
    waveBase[t] = s - v;
    if (t == 15) gTot = s;
  }
  // Phase B(2): 1024-wide exclusive prefix of striped bins
  int bv = binsS[t];
  scan2[t] = bv;
  __syncthreads();
  for (int off = 1; off < 1024; off <<= 1) {
    int v2 = (t >= off) ? scan2[t - off] : 0;
    __syncthreads();
    scan2[t] += v2;
    __syncthreads();
  }
  binsS[t] = scan2[t] - bv;      // exclusive striped placement bases
  __syncthreads();

  // Phase C: coalesced indptr/cursor writes + striped placement
  int run = waveBase[w];
#pragma unroll
  for (int i = 0; i < 25; ++i) {
    int idx = nbase + i * 64 + lane;
    int d = dl[i];
    int s = d;
#pragma unroll
    for (int off = 1; off < 64; off <<= 1) {
      int u = __shfl_up(s, off);
      if (lane >= off) s += u;
    }
    int excl = run + s - d;
    if (idx < N_NODESC) {
      indptr[idx] = excl;
      cursor[idx] = excl;
      int fb = (d > 255 ? 255 : d) * 4 + stripe;
      int pos = atomicAdd(&binsS[fb], 1);
      sorted[pos] = idx;
    }
    run += __shfl(s, 63);        // group total
  }
  if (t == 0) indptr[N_NODESC] = gTot;
}

// packed edge meta: src (16b) | fp16 weight (16b)
__global__ void fill_kernel(const int* __restrict__ ei, const float* __restrict__ ea,
                            int* __restrict__ cursor, unsigned* __restrict__ emeta) {
  int e = blockIdx.x * blockDim.x + threadIdx.x;
  if (e >= N_EDGESC) return;
  int dst = ei[N_EDGESC + e];
  int pos = atomicAdd(&cursor[dst], 1);
  unsigned short hw = __half_as_ushort(__float2half_rn(ea[e]));
  emeta[pos] = (unsigned)ei[e] | ((unsigned)hw << 16);
}

// ================= panel-major CSR gather (L2-blocked, 8 nodes per wave, fp16) =====
// 4-edge unroll, 2 independent accumulator banks (R7-verified best variant).
__global__ __launch_bounds__(256)
void agg_gather_s(const unsigned short* __restrict__ feat, const int* __restrict__ indptr,
                  const unsigned* __restrict__ emeta, const int* __restrict__ sorted,
                  unsigned short* __restrict__ outp, int lgP) {
  int panel = blockIdx.x & ((1 << lgP) - 1);
  int nidx = (blockIdx.x >> lgP) * 32 + (threadIdx.x >> 3);   // 32 node-slots / block
  if (nidx >= N_NODESC) return;
  int c8 = threadIdx.x & 7;
  int node = sorted[nidx];
  int beg = indptr[node];
  int deg = indptr[node + 1] - beg;
  const unsigned* mp = emeta + beg;
  const char* fb = (const char*)(feat + (size_t)panel * PSTRIDE);
  unsigned coff = c8 * 16u;
  float acc0[8] = {}, acc1[8] = {};
  int j = 0;
  for (; j + 4 <= deg; j += 4) {
    unsigned m0_ = mp[j];
    unsigned m1_ = mp[j + 1];
    unsigned m2_ = mp[j + 2];
    unsigned m3_ = mp[j + 3];
    half8 v0 = *(const half8*)(fb + (m0_ & 0xffffu) * 128u + coff);
    half8 v1 = *(const half8*)(fb + (m1_ & 0xffffu) * 128u + coff);
    half8 v2 = *(const half8*)(fb + (m2_ & 0xffffu) * 128u + coff);
    half8 v3 = *(const half8*)(fb + (m3_ & 0xffffu) * 128u + coff);
    float w0 = __half2float(__ushort_as_half((unsigned short)(m0_ >> 16)));
    float w1 = __half2float(__ushort_as_half((unsigned short)(m1_ >> 16)));
    float w2 = __half2float(__ushort_as_half((unsigned short)(m2_ >> 16)));
    float w3 = __half2float(__ushort_as_half((unsigned short)(m3_ >> 16)));
#pragma unroll
    for (int c = 0; c < 8; ++c) acc0[c] += (float)v0[c] * w0;
#pragma unroll
    for (int c = 0; c < 8; ++c) acc1[c] += (float)v1[c] * w1;
#pragma unroll
    for (int c = 0; c < 8; ++c) acc0[c] += (float)v2[c] * w2;
#pragma unroll
    for (int c = 0; c < 8; ++c) acc1[c] += (float)v3[c] * w3;
  }
  if (j + 2 <= deg) {
    unsigned mA = mp[j];
    unsigned mB = mp[j + 1];
    half8 vA = *(const half8*)(fb + (mA & 0xffffu) * 128u + coff);
    half8 vB = *(const half8*)(fb + (mB & 0xffffu) * 128u + coff);
    float wA = __half2float(__ushort_as_half((unsigned short)(mA >> 16)));
    float wB = __half2float(__ushort_as_half((unsigned short)(mB >> 16)));
#pragma unroll
    for (int c = 0; c < 8; ++c) acc0[c] += (float)vA[c] * wA;
#pragma unroll
    for (int c = 0; c < 8; ++c) acc1[c] += (float)vB[c] * wB;
    j += 2;
  }
  if (j < deg) {
    unsigned mA = mp[j];
    half8 vA = *(const half8*)(fb + (mA & 0xffffu) * 128u + coff);
    float wA = __half2float(__ushort_as_half((unsigned short)(mA >> 16)));
#pragma unroll
    for (int c = 0; c < 8; ++c) acc0[c] += (float)vA[c] * wA;
  }
  half8 o;
#pragma unroll
  for (int c = 0; c < 8; ++c) o[c] = (_Float16)(acc0[c] + acc1[c]);
  *(half8*)(outp + (size_t)panel * PSTRIDE + (size_t)node * 64 + c8 * 8) = o;
}

// ---- XCD swizzle for 392-block grid (98 m-tiles of 256 x 4 n-tiles of 128); 392=8*49.
__device__ __forceinline__ void gemm_map4(int b, int& m0, int& n0) {
  int g = (b & 7) * 49 + (b >> 3);   // contiguous chunk per XCD
  m0 = (g >> 2) << 8;                 // 0..24832 (98 m-tiles of 256)
  n0 = (g & 3) << 7;                  // 0,128,256,384
}

// ---- staging (256 thr): linear LDS dest (wave-uniform base + lane*16),
//      pre-swizzled global source (chunk c = (s&7) ^ (row&7)) -- byte-identical
//      swizzle to the proven conflict-free scheme.
//      A-tile 256x64 (32 KB): 8 loads/thread.  B-tile 128x64 (16 KB): 4 loads/thread.
__device__ __forceinline__ void stage_a8(const short* Apan, int m0, int M,
                                         short* dst, int wave, int lane) {
#pragma unroll
  for (int i = 0; i < 8; ++i) {
    int s = ((i * 4 + wave) << 6) + lane;
    int row = s >> 3;                  // 0..255
    int c = (s & 7) ^ (row & 7);
    int rg = m0 + row;
    if (rg > M - 1) rg = M - 1;
    const short* gp = Apan + (size_t)rg * 64 + (c << 3);
    __builtin_amdgcn_global_load_lds(
        (const __attribute__((address_space(1))) void*)gp,
        (__attribute__((address_space(3))) void*)(dst + ((i * 4 + wave) << 9)),
        16, 0, 0);
  }
}

__device__ __forceinline__ void stage_b4(const short* BT, int n0, int K, int kbase,
                                         short* dst, int wave, int lane) {
#pragma unroll
  for (int i = 0; i < 4; ++i) {
    int s = ((i * 4 + wave) << 6) + lane;
    int row = s >> 3;                  // 0..127
    int c = (s & 7) ^ (row & 7);
    const short* gp = BT + (size_t)(n0 + row) * K + kbase + (c << 3);
    __builtin_amdgcn_global_load_lds(
        (const __attribute__((address_space(1))) void*)gp,
        (__attribute__((address_space(3))) void*)(dst + ((i * 4 + wave) << 9)),
        16, 0, 0);
  }
}

__device__ __forceinline__ const short* apan_sel(const short* A0, const short* A1,
                                                 int S, int kt) {
  int kb = kt << 6;
  const short* Ab = (kb < S) ? A0 : A1;
  int koff = (kb < S) ? kb : kb - S;
  return Ab + (size_t)(koff >> 6) * PSTRIDE;
}

// raw barrier + compiler memory fence
__device__ __forceinline__ void wg_barrier() {
  asm volatile("" ::: "memory");
  __builtin_amdgcn_s_barrier();
  asm volatile("" ::: "memory");
}

// ---- gemm_core v3 (R10-verified best, ~36us pool): BM=256, BN=128, BK=64,
//      256 thr (4 waves 2m x 2n, wave-tile 128x64 -> 8x4 frags, 5.3x register
//      reuse, 0.75x LDS bytes/FLOP vs 64x64 tiles).  Single-buffered 48 KB LDS,
//      classic 2-barrier loop; cross-block overlap (2 blocks/CU) hides drains.
//      [R11 lesson: A-direct-from-global regressed 2.2x -- L1 thrash; operands
//       with in-block reuse belong in LDS.]
__device__ __forceinline__ void gemm_core(const short* A0, const short* A1,
                                          const short* BT, int M, int S,
                                          int m0, int n0, short* As, short* Bs,
                                          f32x4 (&acc)[8][4]) {
  const int K = 2 * S;
  const int nk = K >> 6;              // 4 (GEMM1) / 16 (GEMM2)
  const int tid = threadIdx.x;
  const int wave = tid >> 6;
  const int lane = tid & 63;
  const int quad = lane >> 4;
  const int r = lane & 15;
  const int wm = (wave >> 1) << 7;    // 0 or 128
  const int wn = (wave & 1) << 6;     // 0 or 64

  // precomputed LDS fragment short-offsets, static-indexed
  int aoff[2][8], boff[2][4];
#pragma unroll
  for (int p = 0; p < 2; ++p) {
#pragma unroll
    for (int tm = 0; tm < 8; ++tm) {
      int ml = wm + tm * 16 + r;       // 0..255
      int c = (p << 2) + quad;
      aoff[p][tm] = (ml * 8 + (c ^ (ml & 7))) * 8;
    }
#pragma unroll
    for (int tn = 0; tn < 4; ++tn) {
      int nl = wn + tn * 16 + r;       // 0..127
      int c = (p << 2) + quad;
      boff[p][tn] = (nl * 8 + (c ^ (nl & 7))) * 8;
    }
  }

  for (int t = 0; t < nk; ++t) {
    stage_a8(apan_sel(A0, A1, S, t), m0, M, As, wave, lane);
    stage_b4(BT, n0, K, t << 6, Bs, wave, lane);
    asm volatile("s_waitcnt vmcnt(0)");
    wg_barrier();
    // ---------- phase 0 (ks = 0): 12 ds_read_b128 + 32 MFMA
    {
      half8 af[8], bf[4];
#pragma unroll
      for (int tm = 0; tm < 8; ++tm) af[tm] = *(const half8*)&As[aoff[0][tm]];
#pragma unroll
      for (int tn = 0; tn < 4; ++tn) bf[tn] = *(const half8*)&Bs[boff[0][tn]];
      __builtin_amdgcn_s_setprio(1);
#pragma unroll
      for (int tm = 0; tm < 8; ++tm)
#pragma unroll
        for (int tn = 0; tn < 4; ++tn)
          acc[tm][tn] = __builtin_amdgcn_mfma_f32_16x16x32_f16(af[tm], bf[tn], acc[tm][tn], 0, 0, 0);
      __builtin_amdgcn_s_setprio(0);
    }
    // ---------- phase 1 (ks = 1): 12 ds_read_b128 + 32 MFMA
    {
      half8 af[8], bf[4];
#pragma unroll
      for (int tm = 0; tm < 8; ++tm) af[tm] = *(const half8*)&As[aoff[1][tm]];
#pragma unroll
      for (int tn = 0; tn < 4; ++tn) bf[tn] = *(const half8*)&Bs[boff[1][tn]];
      __builtin_amdgcn_s_setprio(1);
#pragma unroll
      for (int tm = 0; tm < 8; ++tm)
#pragma unroll
        for (int tn = 0; tn < 4; ++tn)
          acc[tm][tn] = __builtin_amdgcn_mfma_f32_16x16x32_f16(af[tm], bf[tn], acc[tm][tn], 0, 0, 0);
      __builtin_amdgcn_s_setprio(0);
    }
    wg_barrier();   // protect single-buffered LDS before next stage
  }
}

// ---------------- fp16 MFMA GEMM (A operands PANEL-MAJOR): h1p = relu([A0|A1]@BT^T + b)
__global__ __launch_bounds__(256, 2)
void gemm_bt_relu(const short* __restrict__ A0, const short* __restrict__ A1,
                  const short* __restrict__ BT, const float* __restrict__ bias,
                  unsigned short* __restrict__ Outp, int M, int S) {
  __shared__ __align__(16) short As[256 * 64];   // 32 KB
  __shared__ __align__(16) short Bs[128 * 64];   // 16 KB
  int m0, n0;
  gemm_map4(blockIdx.x, m0, n0);
  const int wave = threadIdx.x >> 6;
  const int lane = threadIdx.x & 63;
  const int quad = lane >> 4;
  const int r = lane & 15;
  const int wm = (wave >> 1) << 7;
  const int wn = (wave & 1) << 6;

  f32x4 acc[8][4] = {};
  gemm_core(A0, A1, BT, M, S, m0, n0, As, Bs, acc);

#pragma unroll
  for (int tm = 0; tm < 8; ++tm) {
    int rowb = m0 + wm + tm * 16 + quad * 4;
#pragma unroll
    for (int tn = 0; tn < 4; ++tn) {
      int col = n0 + wn + tn * 16 + r;
      float bv = bias[col];
      unsigned short* obase = Outp + (size_t)(col >> 6) * PSTRIDE + (col & 63);
#pragma unroll
      for (int reg = 0; reg < 4; ++reg) {
        int rr = rowb + reg;
        if (rr < M) {
          float v = acc[tm][tn][reg] + bv;
          v = v > 0.f ? v : 0.f;
          obase[(size_t)rr * 64] = f2h(v);
        }
      }
    }
  }
}

// ---------------- GEMM2 + fused mean-pool (A panel-major): gsum += per-graph col sums
__global__ __launch_bounds__(256, 2)
void gemm_bt_pool(const short* __restrict__ A0, const short* __restrict__ A1,
                  const short* __restrict__ BT, const float* __restrict__ bias,
                  const int* __restrict__ batch, float* __restrict__ gsum, int M, int S) {
  __shared__ __align__(16) short As[256 * 64];   // 32 KB
  __shared__ __align__(16) short Bs[128 * 64];   // 16 KB
  int m0, n0;
  gemm_map4(blockIdx.x, m0, n0);
  const int wave = threadIdx.x >> 6;
  const int lane = threadIdx.x & 63;
  const int quad = lane >> 4;
  const int r = lane & 15;
  const int wm = (wave >> 1) << 7;
  const int wn = (wave & 1) << 6;

  f32x4 acc[8][4] = {};
  gemm_core(A0, A1, BT, M, S, m0, n0, As, Bs, acc);

  // epilogue: relu(+bias), zero invalid rows, per-graph column sums -> atomicAdd(gsum)
  int gid[8][4];
#pragma unroll
  for (int tm = 0; tm < 8; ++tm) {
    int rowb = m0 + wm + tm * 16 + quad * 4;
#pragma unroll
    for (int reg = 0; reg < 4; ++reg) {
      int rr = rowb + reg;
      gid[tm][reg] = batch[rr < M ? rr : (M - 1)];
    }
#pragma unroll
    for (int tn = 0; tn < 4; ++tn) {
      float bv = bias[n0 + wn + tn * 16 + r];
#pragma unroll
      for (int reg = 0; reg < 4; ++reg) {
        int rr = rowb + reg;
        float v = acc[tm][tn][reg] + bv;
        v = v > 0.f ? v : 0.f;
        acc[tm][tn][reg] = (rr < M) ? v : 0.f;
      }
    }
  }
  int g_lo = batch[m0 < M ? m0 : (M - 1)];
  int g_hi = batch[(m0 + 255) < M ? (m0 + 255) : (M - 1)];
  for (int g = g_lo; g <= g_hi; ++g) {
#pragma unroll
    for (int tn = 0; tn < 4; ++tn) {
      float s = 0.f;
#pragma unroll
      for (int tm = 0; tm < 8; ++tm)
#pragma unroll
        for (int reg = 0; reg < 4; ++reg)
          s += (gid[tm][reg] == g) ? acc[tm][tn][reg] : 0.f;
      s += __shfl_xor(s, 16);
      s += __shfl_xor(s, 32);
      if (quad == 0)
        atomicAdd(&gsum[(size_t)g * HIDC + n0 + wn + tn * 16 + r], s);
    }
  }
}

// ---------------- MLP head (256 threads: 4-way split over the 512-dim input)
__global__ __launch_bounds__(256)
void mlp_kernel(const float* __restrict__ gsum, const int* __restrict__ batch,
                const float* __restrict__ Wl1, const float* __restrict__ bl1,
                const float* __restrict__ Wl2, const float* __restrict__ bl2,
                const float* __restrict__ Wl3, const float* __restrict__ bl3,
                float* __restrict__ out) {
  int gi = blockIdx.x;
  int t = threadIdx.x;
  int unit = t & 63;
  int part = t >> 6;  // 4 parts of 128
  __shared__ float red[4][64];
  __shared__ float h1s[64];
  __shared__ float h2s[16];
  int lo = 0, hi = N_NODESC;
  while (lo < hi) { int mid = (lo + hi) >> 1; if (batch[mid] < gi) lo = mid + 1; else hi = mid; }
  int start = lo;
  hi = N_NODESC;
  while (lo < hi) { int mid = (lo + hi) >> 1; if (batch[mid] < gi + 1) lo = mid + 1; else hi = mid; }
  float inv = 1.0f / fmaxf((float)(lo - start), 1.0f);
  const float* gr = gsum + gi * HIDC;
  float acc = 0.f;
  for (int j = part * 128; j < (part + 1) * 128; ++j)
    acc += gr[j] * Wl1[j * 64 + unit];
  red[part][unit] = acc;
  __syncthreads();
  if (t < 64) {
    float a = bl1[t] + (red[0][t] + red[1][t] + red[2][t] + red[3][t]) * inv;
    h1s[t] = fmaxf(a, 0.f);
  }
  __syncthreads();
  if (t < 16) {
    float a = bl2[t];
    for (int j = 0; j < 64; ++j) a += h1s[j] * Wl2[j * 16 + t];
    h2s[t] = fmaxf(a, 0.f);
  }
  __syncthreads();
  if (t == 0) {
    float a = bl3[0];
    for (int j = 0; j < 16; ++j) a += h2s[j] * Wl3[j];
    out[gi] = a;
  }
}

extern "C" void kernel_launch(void* const* d_in, const int* in_sizes, int n_in,
                              void* d_out, int out_size, void* d_ws, size_t ws_size,
                              hipStream_t stream) {
  const float* x      = (const float*)d_in[0];
  const int*   ei     = (const int*)d_in[1];
  const float* ea     = (const float*)d_in[2];
  const int*   batch  = (const int*)d_in[3];
  const float* W1rel  = (const float*)d_in[4];
  const float* b1     = (const float*)d_in[5];
  const float* W1root = (const float*)d_in[6];
  const float* W2rel  = (const float*)d_in[7];
  const float* b2     = (const float*)d_in[8];
  const float* W2root = (const float*)d_in[9];
  const float* Wl1    = (const float*)d_in[10];
  const float* bl1    = (const float*)d_in[11];
  const float* Wl2    = (const float*)d_in[12];
  const float* bl2    = (const float*)d_in[13];
  const float* Wl3    = (const float*)d_in[14];
  const float* bl3    = (const float*)d_in[15];
  float* out = (float*)d_out;

  // workspace layout (bytes, 16B-aligned). All node features fp16 PANEL-MAJOR [P][25000][64].
  char* ws = (char*)d_ws;
  unsigned short* xp     = (unsigned short*)(ws + 0);           //  6.4 MB (2 panels)
  unsigned short* agg1p  = (unsigned short*)(ws + 6400000);     //  6.4 MB (2 panels)
  unsigned short* h1p    = (unsigned short*)(ws + 12800000);    // 25.6 MB (8 panels)
  unsigned short* agg2p  = (unsigned short*)(ws + 38400000);    // 25.6 MB (8 panels)
  unsigned short* W1T    = (unsigned short*)(ws + 64000000);    // 256 KB
  unsigned short* W2T    = (unsigned short*)(ws + 64262144);    //   1 MB
  float*          gsum   = (float*)(ws + 65310720);             // 128 KB
  int*            deg    = (int*)(ws + 65441792);               // 100 KB + sentinel
  int*            cursor = (int*)(ws + 65541796);               // 100 KB
  int*            indptr = (int*)(ws + 65641796);               // 100 KB+16
  unsigned*       emeta  = (unsigned*)(ws + 65741812);          //  1.6 MB (exact CSR)
  int*            sorted = (int*)(ws + 67341812);               // 100 KB

  // 1) fused prep: deg histogram (uniform-base) + x->fp16 panels + wt + zero gsum
  prep_kernel<<<4976, 256, 0, stream>>>(x, ei, W1rel, W1root, W2rel, W2root,
                                        xp, W1T, W2T, deg, gsum);
  // 2) scan v3 (coalesced; + base subtraction, striped counting sort by degree)
  scan_kernel<<<1, 1024, 0, stream>>>(deg, indptr, cursor, sorted);
  // 3) CSR fill
  fill_kernel<<<(N_EDGESC + 255) / 256, 256, 0, stream>>>(ei, ea, cursor, emeta);

  // 4) layer-1 aggregation: 2 panels (panel = blk&1); 32 nodes/block
  const int NBLK = (N_NODESC + 31) / 32;   // 782
  agg_gather_s<<<NBLK * 2, 256, 0, stream>>>(xp, indptr, emeta, sorted, agg1p, 1);

  // 5) GEMM1: h1p = relu([agg1|x] @ [W1rel;W1root] + b1)   (M=25000, K=256, N=512)
  gemm_bt_relu<<<392, 256, 0, stream>>>((const short*)agg1p, (const short*)xp,
                                        (const short*)W1T, b1, h1p, N_NODESC, 128);

  // 6) layer-2 aggregation: 8 panels (panel = blk&7 -> per-XCD L2-resident)
  agg_gather_s<<<NBLK * 8, 256, 0, stream>>>(h1p, indptr, emeta, sorted, agg2p, 3);

  // 7) GEMM2 + fused mean-pool
  gemm_bt_pool<<<392, 256, 0, stream>>>((const short*)agg2p, (const short*)h1p,
                                        (const short*)W2T, b2, batch, gsum, N_NODESC, 512);

  // 8) MLP head (divides by counts)
  mlp_kernel<<<N_GRAPHSC, 256, 0, stream>>>(gsum, batch, Wl1, bl1, Wl2, bl2, Wl3, bl3, out);
}

// Round 16
// 267.247 us; speedup vs baseline: 1.1946x; 1.0122x over previous
//
#include <hip/hip_runtime.h>
#include <hip/hip_bf16.h>
#include <hip/hip_fp16.h>
#include <stdint.h>

#define N_NODESC 25000
#define N_EDGESC 400000
#define N_GRAPHSC 64
#define F_INC 128
#define HIDC 512
#define PSTRIDE 1600000   // elements per 64-col panel: 25000*64

typedef __attribute__((ext_vector_type(8))) short short8;
typedef __attribute__((ext_vector_type(8))) _Float16 half8;
typedef __attribute__((ext_vector_type(4))) float f32x4;

__device__ __forceinline__ unsigned short f2h(float f) {
  return __half_as_ushort(__float2half_rn(f));
}

// ================= fused prep (1 launch):
//  blocks [0,1563): degree count via atomicAdd on UNIFORM-init deg (poison-agnostic;
//                   true degree recovered in scan via sentinel deg[25000])
//  blocks [1563,4688): x -> fp16 panel-major
//  blocks [4688,4848): weight transposes (LDS tiles)
//  blocks [4848,4976): zero gsum
__global__ __launch_bounds__(256)
void prep_kernel(const float* __restrict__ x, const int* __restrict__ ei,
                 const float* __restrict__ W1rel, const float* __restrict__ W1root,
                 const float* __restrict__ W2rel, const float* __restrict__ W2root,
                 unsigned short* __restrict__ xp, unsigned short* __restrict__ W1T,
                 unsigned short* __restrict__ W2T, int* __restrict__ deg,
                 float* __restrict__ gsum) {
  int blk = blockIdx.x, t = threadIdx.x;
  if (blk < 1563) {                              // degree histogram (no pre-zero needed)
    int e = blk * 256 + t;
    if (e < N_EDGESC) atomicAdd(&deg[ei[N_EDGESC + e]], 1);
  } else if (blk < 4688) {                       // 3125 blocks: 3.2M elems / 4
    int idx = ((blk - 1563) * 256 + t) * 4;
    int node = idx >> 7;
    int col = idx & 127;
    float4 v = *(const float4*)(x + idx);
    ushort4 o;
    o.x = f2h(v.x); o.y = f2h(v.y); o.z = f2h(v.z); o.w = f2h(v.w);
    *(ushort4*)(xp + (size_t)(col >> 6) * PSTRIDE + (size_t)node * 64 + (col & 63)) = o;
  } else if (blk < 4848) {                       // 160 blocks: weight transposes
    __shared__ float tile[64][65];
    int b2 = blk - 4688;
    const float* src;
    unsigned short* dst;
    int n0, k0, Kout;
    if (b2 < 128) {                              // W2: k-tiles 16, n-tiles 8
      int kt = b2 >> 3, nt = b2 & 7;
      k0 = kt * 64; n0 = nt * 64;
      src = (k0 < 512) ? (W2rel + (size_t)k0 * 512) : (W2root + (size_t)(k0 - 512) * 512);
      dst = W2T; Kout = 1024;
    } else {                                     // W1: k-tiles 4, n-tiles 8
      int b = b2 - 128;
      int kt = b >> 3, nt = b & 7;
      k0 = kt * 64; n0 = nt * 64;
      src = (k0 < 128) ? (W1rel + (size_t)k0 * 512) : (W1root + (size_t)(k0 - 128) * 512);
      dst = W1T; Kout = 256;
    }
    int c = t & 63;
    int r4 = t >> 6;
#pragma unroll
    for (int rr = 0; rr < 64; rr += 4) {
      int row = rr + r4;
      tile[c][row] = src[(size_t)row * 512 + n0 + c];
    }
    __syncthreads();
#pragma unroll
    for (int rr = 0; rr < 64; rr += 4) {
      int nrow = rr + r4;
      dst[(size_t)(n0 + nrow) * Kout + k0 + c] = f2h(tile[nrow][c]);
    }
  } else {                                       // 128 blocks: gsum 64x512
    int i = (blk - 4848) * 256 + t;
    if (i < N_GRAPHSC * HIDC) gsum[i] = 0.f;
  }
}

// single-block scan v3 — COALESCED (R9-verified, -22us): wave w owns nodes
// [w*1600, w*1600+1600), lane l handles i*64+l. Per-group shfl_up inclusive
// scans; cross-wave bases via 16-value wave-0 scan; striped degree bins.
__global__ __launch_bounds__(1024)
void scan_kernel(const int* __restrict__ deg, int* __restrict__ indptr, int* __restrict__ cursor,
                 int* __restrict__ sorted) {
  __shared__ int binsS[1024];    // [256 bins][4 stripes], flat f = bin*4 + stripe
  __shared__ int scan2[1024];
  __shared__ int Wsh[16];        // per-wave degree totals
  __shared__ int waveBase[16];   // exclusive prefix of Wsh
  __shared__ int gTot;
  const int t = threadIdx.x;
  const int w = t >> 6;
  const int lane = t & 63;
  const int stripe = t & 3;
  const int nbase = w * 1600;
  const unsigned ub = (unsigned)deg[N_NODESC];   // uniform init value (poison or 0)
  binsS[t] = 0;
  __syncthreads();

  // Phase A: coalesced loads, per-thread dl[], wave totals, striped histogram
  int dl[25];
  int tw = 0;
#pragma unroll
  for (int i = 0; i < 25; ++i) {
    int idx = nbase + i * 64 + lane;
    int d = (idx < N_NODESC) ? (int)((unsigned)deg[idx] - ub) : 0;
    dl[i] = d;
    if (idx < N_NODESC) {
      tw += d;
      atomicAdd(&binsS[(d > 255 ? 255 : d) * 4 + stripe], 1);
    }
  }
#pragma unroll
  for (int off = 32; off > 0; off >>= 1) tw += __shfl_xor(tw, off);
  if (lane == 0) Wsh[w] = tw;
  __syncthreads();               // histogram + Wsh complete

  // Phase B(1): wave-0 scans the 16 wave totals (no barrier inside)
  if (t < 16) {
    int v = Wsh[t];
    int s = v;
#pragma unroll
    for (int off = 1; off < 16; off <<= 1) {
      int u = __shfl_up(s, off);
      if (t >= off) s += u;
    }
    waveBase[t] = s - v;
    if (t == 15) gTot = s;
  }
  // Phase B(2): 1024-wide exclusive prefix of striped bins
  int bv = binsS[t];
  scan2[t] = bv;
  __syncthreads();
  for (int off = 1; off < 1024; off <<= 1) {
    int v2 = (t >= off) ? scan2[t - off] : 0;
    __syncthreads();
    scan2[t] += v2;
    __syncthreads();
  }
  binsS[t] = scan2[t] - bv;      // exclusive striped placement bases
  __syncthreads();

  // Phase C: coalesced indptr/cursor writes + striped placement
  int run = waveBase[w];
#pragma unroll
  for (int i = 0; i < 25; ++i) {
    int idx = nbase + i * 64 + lane;
    int d = dl[i];
    int s = d;
#pragma unroll
    for (int off = 1; off < 64; off <<= 1) {
      int u = __shfl_up(s, off);
      if (lane >= off) s += u;
    }
    int excl = run + s - d;
    if (idx < N_NODESC) {
      indptr[idx] = excl;
      cursor[idx] = excl;
      int fb = (d > 255 ? 255 : d) * 4 + stripe;
      int pos = atomicAdd(&binsS[fb], 1);
      sorted[pos] = idx;
    }
    run += __shfl(s, 63);        // group total
  }
  if (t == 0) indptr[N_NODESC] = gTot;
}

// packed edge meta: src (16b) | fp16 weight (16b)
__global__ void fill_kernel(const int* __restrict__ ei, const float* __restrict__ ea,
                            int* __restrict__ cursor, unsigned* __restrict__ emeta) {
  int e = blockIdx.x * blockDim.x + threadIdx.x;
  if (e >= N_EDGESC) return;
  int dst = ei[N_EDGESC + e];
  int pos = atomicAdd(&cursor[dst], 1);
  unsigned short hw = __half_as_ushort(__float2half_rn(ea[e]));
  emeta[pos] = (unsigned)ei[e] | ((unsigned)hw << 16);
}

// ================= panel-major CSR gather (L2-blocked, 8 nodes per wave, fp16) =====
// 4-edge unroll, 2 independent accumulator banks (R7-verified best variant).
// R13: DESCENDING-degree processing order (node = sorted[N-1-nidx]) -- counting
// sort is ascending, so the longest (high-degree) blocks used to launch LAST and
// bound the dispatch tail; reversed, they start first and short blocks fill in.
__global__ __launch_bounds__(256)
void agg_gather_s(const unsigned short* __restrict__ feat, const int* __restrict__ indptr,
                  const unsigned* __restrict__ emeta, const int* __restrict__ sorted,
                  unsigned short* __restrict__ outp, int lgP) {
  int panel = blockIdx.x & ((1 << lgP) - 1);
  int nidx = (blockIdx.x >> lgP) * 32 + (threadIdx.x >> 3);   // 32 node-slots / block
  if (nidx >= N_NODESC) return;
  int c8 = threadIdx.x & 7;
  int node = sorted[N_NODESC - 1 - nidx];        // descending degree
  int beg = indptr[node];
  int deg = indptr[node + 1] - beg;
  const unsigned* mp = emeta + beg;
  const char* fb = (const char*)(feat + (size_t)panel * PSTRIDE);
  unsigned coff = c8 * 16u;
  float acc0[8] = {}, acc1[8] = {};
  int j = 0;
  for (; j + 4 <= deg; j += 4) {
    unsigned m0_ = mp[j];
    unsigned m1_ = mp[j + 1];
    unsigned m2_ = mp[j + 2];
    unsigned m3_ = mp[j + 3];
    half8 v0 = *(const half8*)(fb + (m0_ & 0xffffu) * 128u + coff);
    half8 v1 = *(const half8*)(fb + (m1_ & 0xffffu) * 128u + coff);
    half8 v2 = *(const half8*)(fb + (m2_ & 0xffffu) * 128u + coff);
    half8 v3 = *(const half8*)(fb + (m3_ & 0xffffu) * 128u + coff);
    float w0 = __half2float(__ushort_as_half((unsigned short)(m0_ >> 16)));
    float w1 = __half2float(__ushort_as_half((unsigned short)(m1_ >> 16)));
    float w2 = __half2float(__ushort_as_half((unsigned short)(m2_ >> 16)));
    float w3 = __half2float(__ushort_as_half((unsigned short)(m3_ >> 16)));
#pragma unroll
    for (int c = 0; c < 8; ++c) acc0[c] += (float)v0[c] * w0;
#pragma unroll
    for (int c = 0; c < 8; ++c) acc1[c] += (float)v1[c] * w1;
#pragma unroll
    for (int c = 0; c < 8; ++c) acc0[c] += (float)v2[c] * w2;
#pragma unroll
    for (int c = 0; c < 8; ++c) acc1[c] += (float)v3[c] * w3;
  }
  if (j + 2 <= deg) {
    unsigned mA = mp[j];
    unsigned mB = mp[j + 1];
    half8 vA = *(const half8*)(fb + (mA & 0xffffu) * 128u + coff);
    half8 vB = *(const half8*)(fb + (mB & 0xffffu) * 128u + coff);
    float wA = __half2float(__ushort_as_half((unsigned short)(mA >> 16)));
    float wB = __half2float(__ushort_as_half((unsigned short)(mB >> 16)));
#pragma unroll
    for (int c = 0; c < 8; ++c) acc0[c] += (float)vA[c] * wA;
#pragma unroll
    for (int c = 0; c < 8; ++c) acc1[c] += (float)vB[c] * wB;
    j += 2;
  }
  if (j < deg) {
    unsigned mA = mp[j];
    half8 vA = *(const half8*)(fb + (mA & 0xffffu) * 128u + coff);
    float wA = __half2float(__ushort_as_half((unsigned short)(mA >> 16)));
#pragma unroll
    for (int c = 0; c < 8; ++c) acc0[c] += (float)vA[c] * wA;
  }
  half8 o;
#pragma unroll
  for (int c = 0; c < 8; ++c) o[c] = (_Float16)(acc0[c] + acc1[c]);
  *(half8*)(outp + (size_t)panel * PSTRIDE + (size_t)node * 64 + c8 * 8) = o;
}

// ---- XCD swizzle for 392-block grid (98 m-tiles of 256 x 4 n-tiles of 128); 392=8*49.
__device__ __forceinline__ void gemm_map4(int b, int& m0, int& n0) {
  int g = (b & 7) * 49 + (b >> 3);   // contiguous chunk per XCD
  m0 = (g >> 2) << 8;                 // 0..24832 (98 m-tiles of 256)
  n0 = (g & 3) << 7;                  // 0,128,256,384
}

// ---- staging (256 thr): linear LDS dest (wave-uniform base + lane*16),
//      pre-swizzled global source (chunk c = (s&7) ^ (row&7)) -- byte-identical
//      swizzle to the proven conflict-free scheme.
//      A-tile 256x64 (32 KB): 8 loads/thread.  B-tile 128x64 (16 KB): 4 loads/thread.
__device__ __forceinline__ void stage_a8(const short* Apan, int m0, int M,
                                         short* dst, int wave, int lane) {
#pragma unroll
  for (int i = 0; i < 8; ++i) {
    int s = ((i * 4 + wave) << 6) + lane;
    int row = s >> 3;                  // 0..255
    int c = (s & 7) ^ (row & 7);
    int rg = m0 + row;
    if (rg > M - 1) rg = M - 1;
    const short* gp = Apan + (size_t)rg * 64 + (c << 3);
    __builtin_amdgcn_global_load_lds(
        (const __attribute__((address_space(1))) void*)gp,
        (__attribute__((address_space(3))) void*)(dst + ((i * 4 + wave) << 9)),
        16, 0, 0);
  }
}

__device__ __forceinline__ void stage_b4(const short* BT, int n0, int K, int kbase,
                                         short* dst, int wave, int lane) {
#pragma unroll
  for (int i = 0; i < 4; ++i) {
    int s = ((i * 4 + wave) << 6) + lane;
    int row = s >> 3;                  // 0..127
    int c = (s & 7) ^ (row & 7);
    const short* gp = BT + (size_t)(n0 + row) * K + kbase + (c << 3);
    __builtin_amdgcn_global_load_lds(
        (const __attribute__((address_space(1))) void*)gp,
        (__attribute__((address_space(3))) void*)(dst + ((i * 4 + wave) << 9)),
        16, 0, 0);
  }
}

__device__ __forceinline__ const short* apan_sel(const short* A0, const short* A1,
                                                 int S, int kt) {
  int kb = kt << 6;
  const short* Ab = (kb < S) ? A0 : A1;
  int koff = (kb < S) ? kb : kb - S;
  return Ab + (size_t)(koff >> 6) * PSTRIDE;
}

// raw barrier + compiler memory fence
__device__ __forceinline__ void wg_barrier() {
  asm volatile("" ::: "memory");
  __builtin_amdgcn_s_barrier();
  asm volatile("" ::: "memory");
}

// ---- gemm_core v3 (R10-verified best, ~36us pool): BM=256, BN=128, BK=64,
//      256 thr (4 waves 2m x 2n, wave-tile 128x64 -> 8x4 frags, 5.3x register
//      reuse, 0.75x LDS bytes/FLOP vs 64x64 tiles).  Single-buffered 48 KB LDS,
//      classic 2-barrier loop; cross-block overlap (2 blocks/CU) hides drains.
//      [R11 lesson: A-direct-from-global regressed 2.2x -- L1 thrash; operands
//       with in-block reuse belong in LDS.]
__device__ __forceinline__ void gemm_core(const short* A0, const short* A1,
                                          const short* BT, int M, int S,
                                          int m0, int n0, short* As, short* Bs,
                                          f32x4 (&acc)[8][4]) {
  const int K = 2 * S;
  const int nk = K >> 6;              // 4 (GEMM1) / 16 (GEMM2)
  const int tid = threadIdx.x;
  const int wave = tid >> 6;
  const int lane = tid & 63;
  const int quad = lane >> 4;
  const int r = lane & 15;
  const int wm = (wave >> 1) << 7;    // 0 or 128
  const int wn = (wave & 1) << 6;     // 0 or 64

  // precomputed LDS fragment short-offsets, static-indexed
  int aoff[2][8], boff[2][4];
#pragma unroll
  for (int p = 0; p < 2; ++p) {
#pragma unroll
    for (int tm = 0; tm < 8; ++tm) {
      int ml = wm + tm * 16 + r;       // 0..255
      int c = (p << 2) + quad;
      aoff[p][tm] = (ml * 8 + (c ^ (ml & 7))) * 8;
    }
#pragma unroll
    for (int tn = 0; tn < 4; ++tn) {
      int nl = wn + tn * 16 + r;       // 0..127
      int c = (p << 2) + quad;
      boff[p][tn] = (nl * 8 + (c ^ (nl & 7))) * 8;
    }
  }

  for (int t = 0; t < nk; ++t) {
    stage_a8(apan_sel(A0, A1, S, t), m0, M, As, wave, lane);
    stage_b4(BT, n0, K, t << 6, Bs, wave, lane);
    asm volatile("s_waitcnt vmcnt(0)");
    wg_barrier();
    // ---------- phase 0 (ks = 0): 12 ds_read_b128 + 32 MFMA
    {
      half8 af[8], bf[4];
#pragma unroll
      for (int tm = 0; tm < 8; ++tm) af[tm] = *(const half8*)&As[aoff[0][tm]];
#pragma unroll
      for (int tn = 0; tn < 4; ++tn) bf[tn] = *(const half8*)&Bs[boff[0][tn]];
      __builtin_amdgcn_s_setprio(1);
#pragma unroll
      for (int tm = 0; tm < 8; ++tm)
#pragma unroll
        for (int tn = 0; tn < 4; ++tn)
          acc[tm][tn] = __builtin_amdgcn_mfma_f32_16x16x32_f16(af[tm], bf[tn], acc[tm][tn], 0, 0, 0);
      __builtin_amdgcn_s_setprio(0);
    }
    // ---------- phase 1 (ks = 1): 12 ds_read_b128 + 32 MFMA
    {
      half8 af[8], bf[4];
#pragma unroll
      for (int tm = 0; tm < 8; ++tm) af[tm] = *(const half8*)&As[aoff[1][tm]];
#pragma unroll
      for (int tn = 0; tn < 4; ++tn) bf[tn] = *(const half8*)&Bs[boff[1][tn]];
      __builtin_amdgcn_s_setprio(1);
#pragma unroll
      for (int tm = 0; tm < 8; ++tm)
#pragma unroll
        for (int tn = 0; tn < 4; ++tn)
          acc[tm][tn] = __builtin_amdgcn_mfma_f32_16x16x32_f16(af[tm], bf[tn], acc[tm][tn], 0, 0, 0);
      __builtin_amdgcn_s_setprio(0);
    }
    wg_barrier();   // protect single-buffered LDS before next stage
  }
}

// ---------------- fp16 MFMA GEMM (A operands PANEL-MAJOR): h1p = relu([A0|A1]@BT^T + b)
__global__ __launch_bounds__(256, 2)
void gemm_bt_relu(const short* __restrict__ A0, const short* __restrict__ A1,
                  const short* __restrict__ BT, const float* __restrict__ bias,
                  unsigned short* __restrict__ Outp, int M, int S) {
  __shared__ __align__(16) short As[256 * 64];   // 32 KB
  __shared__ __align__(16) short Bs[128 * 64];   // 16 KB
  int m0, n0;
  gemm_map4(blockIdx.x, m0, n0);
  const int wave = threadIdx.x >> 6;
  const int lane = threadIdx.x & 63;
  const int quad = lane >> 4;
  const int r = lane & 15;
  const int wm = (wave >> 1) << 7;
  const int wn = (wave & 1) << 6;

  f32x4 acc[8][4] = {};
  gemm_core(A0, A1, BT, M, S, m0, n0, As, Bs, acc);

#pragma unroll
  for (int tm = 0; tm < 8; ++tm) {
    int rowb = m0 + wm + tm * 16 + quad * 4;
#pragma unroll
    for (int tn = 0; tn < 4; ++tn) {
      int col = n0 + wn + tn * 16 + r;
      float bv = bias[col];
      unsigned short* obase = Outp + (size_t)(col >> 6) * PSTRIDE + (col & 63);
#pragma unroll
      for (int reg = 0; reg < 4; ++reg) {
        int rr = rowb + reg;
        if (rr < M) {
          float v = acc[tm][tn][reg] + bv;
          v = v > 0.f ? v : 0.f;
          obase[(size_t)rr * 64] = f2h(v);
        }
      }
    }
  }
}

// ---------------- GEMM2 + fused mean-pool (A panel-major): gsum += per-graph col sums
__global__ __launch_bounds__(256, 2)
void gemm_bt_pool(const short* __restrict__ A0, const short* __restrict__ A1,
                  const short* __restrict__ BT, const float* __restrict__ bias,
                  const int* __restrict__ batch, float* __restrict__ gsum, int M, int S) {
  __shared__ __align__(16) short As[256 * 64];   // 32 KB
  __shared__ __align__(16) short Bs[128 * 64];   // 16 KB
  int m0, n0;
  gemm_map4(blockIdx.x, m0, n0);
  const int wave = threadIdx.x >> 6;
  const int lane = threadIdx.x & 63;
  const int quad = lane >> 4;
  const int r = lane & 15;
  const int wm = (wave >> 1) << 7;
  const int wn = (wave & 1) << 6;

  f32x4 acc[8][4] = {};
  gemm_core(A0, A1, BT, M, S, m0, n0, As, Bs, acc);

  // epilogue: relu(+bias), zero invalid rows, per-graph column sums -> atomicAdd(gsum)
  int gid[8][4];
#pragma unroll
  for (int tm = 0; tm < 8; ++tm) {
    int rowb = m0 + wm + tm * 16 + quad * 4;
#pragma unroll
    for (int reg = 0; reg < 4; ++reg) {
      int rr = rowb + reg;
      gid[tm][reg] = batch[rr < M ? rr : (M - 1)];
    }
#pragma unroll
    for (int tn = 0; tn < 4; ++tn) {
      float bv = bias[n0 + wn + tn * 16 + r];
#pragma unroll
      for (int reg = 0; reg < 4; ++reg) {
        int rr = rowb + reg;
        float v = acc[tm][tn][reg] + bv;
        v = v > 0.f ? v : 0.f;
        acc[tm][tn][reg] = (rr < M) ? v : 0.f;
      }
    }
  }
  int g_lo = batch[m0 < M ? m0 : (M - 1)];
  int g_hi = batch[(m0 + 255) < M ? (m0 + 255) : (M - 1)];
  for (int g = g_lo; g <= g_hi; ++g) {
#pragma unroll
    for (int tn = 0; tn < 4; ++tn) {
      float s = 0.f;
#pragma unroll
      for (int tm = 0; tm < 8; ++tm)
#pragma unroll
        for (int reg = 0; reg < 4; ++reg)
          s += (gid[tm][reg] == g) ? acc[tm][tn][reg] : 0.f;
      s += __shfl_xor(s, 16);
      s += __shfl_xor(s, 32);
      if (quad == 0)
        atomicAdd(&gsum[(size_t)g * HIDC + n0 + wn + tn * 16 + r], s);
    }
  }
}

// ---------------- MLP head (256 threads: 4-way split over the 512-dim input)
__global__ __launch_bounds__(256)
void mlp_kernel(const float* __restrict__ gsum, const int* __restrict__ batch,
                const float* __restrict__ Wl1, const float* __restrict__ bl1,
                const float* __restrict__ Wl2, const float* __restrict__ bl2,
                const float* __restrict__ Wl3, const float* __restrict__ bl3,
                float* __restrict__ out) {
  int gi = blockIdx.x;
  int t = threadIdx.x;
  int unit = t & 63;
  int part = t >> 6;  // 4 parts of 128
  __shared__ float red[4][64];
  __shared__ float h1s[64];
  __shared__ float h2s[16];
  int lo = 0, hi = N_NODESC;
  while (lo < hi) { int mid = (lo + hi) >> 1; if (batch[mid] < gi) lo = mid + 1; else hi = mid; }
  int start = lo;
  hi = N_NODESC;
  while (lo < hi) { int mid = (lo + hi) >> 1; if (batch[mid] < gi + 1) lo = mid + 1; else hi = mid; }
  float inv = 1.0f / fmaxf((float)(lo - start), 1.0f);
  const float* gr = gsum + gi * HIDC;
  float acc = 0.f;
  for (int j = part * 128; j < (part + 1) * 128; ++j)
    acc += gr[j] * Wl1[j * 64 + unit];
  red[part][unit] = acc;
  __syncthreads();
  if (t < 64) {
    float a = bl1[t] + (red[0][t] + red[1][t] + red[2][t] + red[3][t]) * inv;
    h1s[t] = fmaxf(a, 0.f);
  }
  __syncthreads();
  if (t < 16) {
    float a = bl2[t];
    for (int j = 0; j < 64; ++j) a += h1s[j] * Wl2[j * 16 + t];
    h2s[t] = fmaxf(a, 0.f);
  }
  __syncthreads();
  if (t == 0) {
    float a = bl3[0];
    for (int j = 0; j < 16; ++j) a += h2s[j] * Wl3[j];
    out[gi] = a;
  }
}

extern "C" void kernel_launch(void* const* d_in, const int* in_sizes, int n_in,
                              void* d_out, int out_size, void* d_ws, size_t ws_size,
                              hipStream_t stream) {
  const float* x      = (const float*)d_in[0];
  const int*   ei     = (const int*)d_in[1];
  const float* ea     = (const float*)d_in[2];
  const int*   batch  = (const int*)d_in[3];
  const float* W1rel  = (const float*)d_in[4];
  const float* b1     = (const float*)d_in[5];
  const float* W1root = (const float*)d_in[6];
  const float* W2rel  = (const float*)d_in[7];
  const float* b2     = (const float*)d_in[8];
  const float* W2root = (const float*)d_in[9];
  const float* Wl1    = (const float*)d_in[10];
  const float* bl1    = (const float*)d_in[11];
  const float* Wl2    = (const float*)d_in[12];
  const float* bl2    = (const float*)d_in[13];
  const float* Wl3    = (const float*)d_in[14];
  const float* bl3    = (const float*)d_in[15];
  float* out = (float*)d_out;

  // workspace layout (bytes, 16B-aligned). All node features fp16 PANEL-MAJOR [P][25000][64].
  char* ws = (char*)d_ws;
  unsigned short* xp     = (unsigned short*)(ws + 0);           //  6.4 MB (2 panels)
  unsigned short* agg1p  = (unsigned short*)(ws + 6400000);     //  6.4 MB (2 panels)
  unsigned short* h1p    = (unsigned short*)(ws + 12800000);    // 25.6 MB (8 panels)
  unsigned short* agg2p  = (unsigned short*)(ws + 38400000);    // 25.6 MB (8 panels)
  unsigned short* W1T    = (unsigned short*)(ws + 64000000);    // 256 KB
  unsigned short* W2T    = (unsigned short*)(ws + 64262144);    //   1 MB
  float*          gsum   = (float*)(ws + 65310720);             // 128 KB
  int*            deg    = (int*)(ws + 65441792);               // 100 KB + sentinel
  int*            cursor = (int*)(ws + 65541796);               // 100 KB
  int*            indptr = (int*)(ws + 65641796);               // 100 KB+16
  unsigned*       emeta  = (unsigned*)(ws + 65741812);          //  1.6 MB (exact CSR)
  int*            sorted = (int*)(ws + 67341812);               // 100 KB

  // 1) fused prep: deg histogram (uniform-base) + x->fp16 panels + wt + zero gsum
  prep_kernel<<<4976, 256, 0, stream>>>(x, ei, W1rel, W1root, W2rel, W2root,
                                        xp, W1T, W2T, deg, gsum);
  // 2) scan v3 (coalesced; + base subtraction, striped counting sort by degree)
  scan_kernel<<<1, 1024, 0, stream>>>(deg, indptr, cursor, sorted);
  // 3) CSR fill
  fill_kernel<<<(N_EDGESC + 255) / 256, 256, 0, stream>>>(ei, ea, cursor, emeta);

  // 4) layer-1 aggregation: 2 panels (panel = blk&1); 32 nodes/block
  const int NBLK = (N_NODESC + 31) / 32;   // 782
  agg_gather_s<<<NBLK * 2, 256, 0, stream>>>(xp, indptr, emeta, sorted, agg1p, 1);

  // 5) GEMM1: h1p = relu([agg1|x] @ [W1rel;W1root] + b1)   (M=25000, K=256, N=512)
  gemm_bt_relu<<<392, 256, 0, stream>>>((const short*)agg1p, (const short*)xp,
                                        (const short*)W1T, b1, h1p, N_NODESC, 128);

  // 6) layer-2 aggregation: 8 panels (panel = blk&7 -> per-XCD L2-resident)
  agg_gather_s<<<NBLK * 8, 256, 0, stream>>>(h1p, indptr, emeta, sorted, agg2p, 3);

  // 7) GEMM2 + fused mean-pool
  gemm_bt_pool<<<392, 256, 0, stream>>>((const short*)agg2p, (const short*)h1p,
                                        (const short*)W2T, b2, batch, gsum, N_NODESC, 512);

  // 8) MLP head (divides by counts)
  mlp_kernel<<<N_GRAPHSC, 256, 0, stream>>>(gsum, batch, Wl1, bl1, Wl2, bl2, Wl3, bl3, out);
}